// Round 3
// baseline (144.244 us; speedup 1.0000x reference)
//
#include <hip/hip_runtime.h>
#include <hip/hip_bf16.h>
#include <hip/hip_cooperative_groups.h>

namespace cg = cooperative_groups;

#define B_SZ 1024
#define F_SZ 2048
#define NK   32
#define NCOL 256            // NK*KD
#define OUTF 2080           // F + NK
#define KS   8              // GEMM split-K
#define NBLK 256
#define NTHR 512

typedef __attribute__((ext_vector_type(8))) short short8v;
typedef __attribute__((ext_vector_type(8))) unsigned short ushort8v;
typedef __attribute__((ext_vector_type(4))) float f32x4;

static __device__ __forceinline__ unsigned short f2bf(float v) {
  __hip_bfloat16 h = __float2bfloat16(v);   // RNE
  return reinterpret_cast<unsigned short&>(h);
}

// ---------------------------------------------------------------------------
// Phase A: copy x rows into out (x part of the concat). 524288 float4 total.
// ---------------------------------------------------------------------------
static __device__ __forceinline__ void dev_copy_x(
    const float* __restrict__ x, float* __restrict__ out, int gtid) {
  const float4* x4 = reinterpret_cast<const float4*>(x);
#pragma unroll
  for (int it = 0; it < 4; ++it) {
    int idx = gtid + it * (NBLK * NTHR);
    int i  = idx >> 9;          // 512 float4 per x row
    int c4 = idx & 511;
    float4 v = x4[idx];
    *reinterpret_cast<float4*>(&out[(size_t)i * OUTF + c4 * 4]) = v;  // 16B-aligned (8320B row base)
  }
}

// ---------------------------------------------------------------------------
// Phase B: bf16 MFMA GEMM partials, f32 inputs converted inline.
// BM=128 BN=64 BK=32, split-K=8, K-chunk=256. 8 waves (4x2), wave tile 32x32.
// part[ks][i][n] = x[i, chunk] . W[chunk, n]
// ---------------------------------------------------------------------------
static __device__ __forceinline__ void dev_gemm(
    const float* __restrict__ x, const float* __restrict__ W,
    float* __restrict__ part, int vb, int t) {
  __shared__ __align__(16) unsigned short As[128][40];  // [row][k], +16B pad
  __shared__ __align__(16) unsigned short Bs[64][40];   // [col(n)][k]

  int mt = vb & 7, nt = (vb >> 3) & 3, ks = vb >> 5;
  int i0 = mt * 128, n0 = nt * 64, kbase = ks * (F_SZ / KS);

  int w = t >> 6, l = t & 63;
  int wr = w >> 1, wc = w & 1;      // wave grid 4x2
  int hi = l >> 4, r16 = l & 15;

  int arow = t >> 2, acq = (t & 3) * 8;     // A staging: 8 f32 -> ushort8
  int wkrow = t >> 4, wn4 = (t & 15) * 4;   // W staging: float4, transposed write

  f32x4 acc[2][2];
#pragma unroll
  for (int mi = 0; mi < 2; ++mi)
#pragma unroll
    for (int ni = 0; ni < 2; ++ni) acc[mi][ni] = (f32x4)(0.f);

  for (int kk = 0; kk < F_SZ / KS; kk += 32) {
    const float* ap = &x[(size_t)(i0 + arow) * F_SZ + kbase + kk + acq];
    float4 av0 = *reinterpret_cast<const float4*>(ap);
    float4 av1 = *reinterpret_cast<const float4*>(ap + 4);
    float4 wv = *reinterpret_cast<const float4*>(
        &W[(size_t)(kbase + kk + wkrow) * NCOL + n0 + wn4]);

    __syncthreads();   // previous iter's frag reads done before overwrite
    ushort8v a8;
    a8[0] = f2bf(av0.x); a8[1] = f2bf(av0.y); a8[2] = f2bf(av0.z); a8[3] = f2bf(av0.w);
    a8[4] = f2bf(av1.x); a8[5] = f2bf(av1.y); a8[6] = f2bf(av1.z); a8[7] = f2bf(av1.w);
    *reinterpret_cast<ushort8v*>(&As[arow][acq]) = a8;
    Bs[wn4 + 0][wkrow] = f2bf(wv.x);          // transposed scatter (inline W^T)
    Bs[wn4 + 1][wkrow] = f2bf(wv.y);
    Bs[wn4 + 2][wkrow] = f2bf(wv.z);
    Bs[wn4 + 3][wkrow] = f2bf(wv.w);
    __syncthreads();

    short8v af[2], bfr[2];
#pragma unroll
    for (int mi = 0; mi < 2; ++mi)
      af[mi] = *reinterpret_cast<const short8v*>(&As[wr * 32 + mi * 16 + r16][hi * 8]);
#pragma unroll
    for (int ni = 0; ni < 2; ++ni)
      bfr[ni] = *reinterpret_cast<const short8v*>(&Bs[wc * 32 + ni * 16 + r16][hi * 8]);
#pragma unroll
    for (int mi = 0; mi < 2; ++mi)
#pragma unroll
      for (int ni = 0; ni < 2; ++ni)
        acc[mi][ni] = __builtin_amdgcn_mfma_f32_16x16x32_bf16(
            af[mi], bfr[ni], acc[mi][ni], 0, 0, 0);
  }

  float* dst = part + (size_t)ks * B_SZ * NCOL;
#pragma unroll
  for (int mi = 0; mi < 2; ++mi)
#pragma unroll
    for (int ni = 0; ni < 2; ++ni)
#pragma unroll
      for (int r = 0; r < 4; ++r) {
        int gi = i0 + wr * 32 + mi * 16 + hi * 4 + r;   // C/D: col=lane&15, row=(lane>>4)*4+reg
        int gn = n0 + wc * 32 + ni * 16 + r16;
        dst[(size_t)gi * NCOL + gn] = acc[mi][ni][r];
      }
}

// ---------------------------------------------------------------------------
// Phase C: reduce split-K partials -> m[1024][256] f32
// ---------------------------------------------------------------------------
static __device__ __forceinline__ void dev_reduce(
    const float* __restrict__ part, float* __restrict__ m, int gtid) {
  if (gtid < B_SZ * NCOL / 4) {
    const float4* p4 = reinterpret_cast<const float4*>(part);
    float4 s = make_float4(0.f, 0.f, 0.f, 0.f);
#pragma unroll
    for (int ks = 0; ks < KS; ++ks) {
      float4 v = p4[(size_t)ks * (B_SZ * NCOL / 4) + gtid];
      s.x += v.x; s.y += v.y; s.z += v.z; s.w += v.w;
    }
    reinterpret_cast<float4*>(m)[gtid] = s;
  }
}

// ---------------------------------------------------------------------------
// Phase D: pairwise L1 + exp partial sums (VALU-bound; m is 1 MB = cache-resident).
// vb = bi(32 i-tiles) x bj(8 j-chunks); thread: k = t&31, owns 2 rows.
// mbp[bj][i][k] = sum_{j in chunk} exp(-L1(m[i,k,:], m[j,k,:]))
// ---------------------------------------------------------------------------
static __device__ __forceinline__ void dev_pairwise(
    const float* __restrict__ m, float* __restrict__ mbp, int vb, int t) {
  int bi = vb & 31;
  int bj = vb >> 5;
  int k = t & 31;
  int g = t >> 5;
  int i0 = bi * 32 + g * 2;
  int j0 = bj * 128;

  const float4* mv = reinterpret_cast<const float4*>(m);
  float4 a0 = mv[(size_t)i0 * 64 + k * 2];
  float4 a1 = mv[(size_t)i0 * 64 + k * 2 + 1];
  float4 b0 = mv[(size_t)(i0 + 1) * 64 + k * 2];
  float4 b1 = mv[(size_t)(i0 + 1) * 64 + k * 2 + 1];

  float acc0 = 0.f, acc1 = 0.f;
#pragma unroll 4
  for (int jj = 0; jj < 128; ++jj) {
    int j = j0 + jj;
    float4 c0 = mv[(size_t)j * 64 + k * 2];
    float4 c1 = mv[(size_t)j * 64 + k * 2 + 1];
    float s0 = fabsf(a0.x - c0.x) + fabsf(a0.y - c0.y) +
               fabsf(a0.z - c0.z) + fabsf(a0.w - c0.w) +
               fabsf(a1.x - c1.x) + fabsf(a1.y - c1.y) +
               fabsf(a1.z - c1.z) + fabsf(a1.w - c1.w);
    float s1 = fabsf(b0.x - c0.x) + fabsf(b0.y - c0.y) +
               fabsf(b0.z - c0.z) + fabsf(b0.w - c0.w) +
               fabsf(b1.x - c1.x) + fabsf(b1.y - c1.y) +
               fabsf(b1.z - c1.z) + fabsf(b1.w - c1.w);
    acc0 += __expf(-s0);
    acc1 += __expf(-s1);
  }
  mbp[((size_t)bj * B_SZ + i0) * NK + k]     = acc0;
  mbp[((size_t)bj * B_SZ + i0 + 1) * NK + k] = acc1;
}

// ---------------------------------------------------------------------------
// Phase E: out[i][2048+k] = sum over 8 j-chunks
// ---------------------------------------------------------------------------
static __device__ __forceinline__ void dev_finalize(
    const float* __restrict__ mbp, float* __restrict__ out, int gtid) {
  if (gtid < B_SZ * NK) {
    int i = gtid >> 5, k = gtid & 31;
    float s = 0.f;
#pragma unroll
    for (int c = 0; c < 8; ++c) s += mbp[((size_t)c * B_SZ + i) * NK + k];
    out[(size_t)i * OUTF + F_SZ + k] = s;
  }
}

// ---------------------------------------------------------------------------
// Fused cooperative kernel: all phases, 3 grid syncs, zero launch gaps.
// ---------------------------------------------------------------------------
__global__ __launch_bounds__(NTHR) void fused_all(
    const float* __restrict__ x, const float* __restrict__ W,
    float* __restrict__ out, float* __restrict__ part,
    float* __restrict__ m, float* __restrict__ mbp) {
  cg::grid_group grid = cg::this_grid();
  int gtid = blockIdx.x * NTHR + threadIdx.x;
  dev_copy_x(x, out, gtid);
  dev_gemm(x, W, part, blockIdx.x, threadIdx.x);
  grid.sync();
  dev_reduce(part, m, gtid);
  grid.sync();
  dev_pairwise(m, mbp, blockIdx.x, threadIdx.x);
  grid.sync();
  dev_finalize(mbp, out, gtid);
}

// --------------------------- fallback (non-coop) ----------------------------
__global__ __launch_bounds__(NTHR) void phaseAB_k(
    const float* __restrict__ x, const float* __restrict__ W,
    float* __restrict__ out, float* __restrict__ part) {
  dev_copy_x(x, out, blockIdx.x * NTHR + threadIdx.x);
  dev_gemm(x, W, part, blockIdx.x, threadIdx.x);
}
__global__ __launch_bounds__(NTHR) void phaseC_k(
    const float* __restrict__ part, float* __restrict__ m) {
  dev_reduce(part, m, blockIdx.x * NTHR + threadIdx.x);
}
__global__ __launch_bounds__(NTHR) void phaseD_k(
    const float* __restrict__ m, float* __restrict__ mbp) {
  dev_pairwise(m, mbp, blockIdx.x, threadIdx.x);
}
__global__ __launch_bounds__(NTHR) void phaseE_k(
    const float* __restrict__ mbp, float* __restrict__ out) {
  dev_finalize(mbp, out, blockIdx.x * NTHR + threadIdx.x);
}

extern "C" void kernel_launch(void* const* d_in, const int* in_sizes, int n_in,
                              void* d_out, int out_size, void* d_ws, size_t ws_size,
                              hipStream_t stream) {
  const float* x = (const float*)d_in[0];
  const float* W = (const float*)d_in[1];
  float* out = (float*)d_out;
  char* ws = (char*)d_ws;

  const size_t MB = 1u << 20;
  float* part = (float*)ws;               // 8 MB
  float* m    = (float*)(ws + 8 * MB);    // 1 MB
  float* mbp  = (float*)(ws + 9 * MB);    // 1 MB

  void* args[] = {(void*)&x, (void*)&W, (void*)&out, (void*)&part, (void*)&m, (void*)&mbp};
  hipError_t e = hipLaunchCooperativeKernel((const void*)fused_all, dim3(NBLK), dim3(NTHR),
                                            args, 0, stream);
  if (e != hipSuccess) {
    // deterministic fallback: same device code as 4 plain kernels
    phaseAB_k<<<dim3(NBLK), NTHR, 0, stream>>>(x, W, out, part);
    phaseC_k<<<dim3(64), NTHR, 0, stream>>>(part, m);
    phaseD_k<<<dim3(NBLK), NTHR, 0, stream>>>(m, mbp);
    phaseE_k<<<dim3(64), NTHR, 0, stream>>>(mbp, out);
  }
}

// Round 4
// 82.368 us; speedup vs baseline: 1.7512x; 1.7512x over previous
//
#include <hip/hip_runtime.h>
#include <hip/hip_bf16.h>

#define B_SZ 1024
#define F_SZ 2048
#define NK   32
#define NCOL 256            // NK*KD
#define OUTF 2080           // F + NK
#define NTHR 512

typedef __attribute__((ext_vector_type(8))) short short8v;
typedef __attribute__((ext_vector_type(8))) unsigned short ushort8v;
typedef __attribute__((ext_vector_type(4))) float f32x4;

static __device__ __forceinline__ unsigned short f2bf(float v) {
  __hip_bfloat16 h = __float2bfloat16(v);   // RNE
  return reinterpret_cast<unsigned short&>(h);
}

// ---------------------------------------------------------------------------
// K1: role-split.
//   blocks 0..31   : full-K bf16 MFMA GEMM -> m[1024][256] (f32), inline cvt
//   blocks 32..255 : copy x rows into out[:, 0:2048]
// GEMM: BM=128 BN=64 BK=32, 8 waves (4x2), wave tile 32x32 (2x2 16x16x32 frags)
// ---------------------------------------------------------------------------
__global__ __launch_bounds__(NTHR) void k1_gemm_copy(
    const float* __restrict__ x, const float* __restrict__ W,
    float* __restrict__ m, float* __restrict__ out) {
  __shared__ __align__(16) unsigned short As[128][40];  // [row][k], +16B pad
  __shared__ __align__(16) unsigned short Bs[64][40];   // [col(n)][k]

  int bid = blockIdx.x;
  int t = threadIdx.x;

  if (bid >= 32) {
    // ------- copy role: 224 blocks, grid-stride over 524288 float4 -------
    const float4* x4 = reinterpret_cast<const float4*>(x);
    int idx = (bid - 32) * NTHR + t;
    const int stride = 224 * NTHR;
    for (; idx < B_SZ * F_SZ / 4; idx += stride) {
      int i  = idx >> 9;          // 512 float4 per x row
      int c4 = idx & 511;
      float4 v = x4[idx];
      *reinterpret_cast<float4*>(&out[(size_t)i * OUTF + c4 * 4]) = v;
    }
    return;
  }

  // ------- GEMM role: 32 blocks (8 mt x 4 nt), K = 2048 full -------
  int mt = bid & 7, nt = bid >> 3;
  int i0 = mt * 128, n0 = nt * 64;

  int w = t >> 6, l = t & 63;
  int wr = w >> 1, wc = w & 1;      // wave grid 4x2
  int hi = l >> 4, r16 = l & 15;

  int arow = t >> 2, acq = (t & 3) * 8;     // A staging: 8 f32 -> ushort8
  int wkrow = t >> 4, wn4 = (t & 15) * 4;   // W staging: float4, transposed write

  f32x4 acc[2][2];
#pragma unroll
  for (int mi = 0; mi < 2; ++mi)
#pragma unroll
    for (int ni = 0; ni < 2; ++ni) acc[mi][ni] = (f32x4)(0.f);

  for (int kk = 0; kk < F_SZ; kk += 32) {
    const float* ap = &x[(size_t)(i0 + arow) * F_SZ + kk + acq];
    float4 av0 = *reinterpret_cast<const float4*>(ap);
    float4 av1 = *reinterpret_cast<const float4*>(ap + 4);
    float4 wv = *reinterpret_cast<const float4*>(
        &W[(size_t)(kk + wkrow) * NCOL + n0 + wn4]);

    __syncthreads();   // previous iter's frag reads done before overwrite
    ushort8v a8;
    a8[0] = f2bf(av0.x); a8[1] = f2bf(av0.y); a8[2] = f2bf(av0.z); a8[3] = f2bf(av0.w);
    a8[4] = f2bf(av1.x); a8[5] = f2bf(av1.y); a8[6] = f2bf(av1.z); a8[7] = f2bf(av1.w);
    *reinterpret_cast<ushort8v*>(&As[arow][acq]) = a8;
    Bs[wn4 + 0][wkrow] = f2bf(wv.x);          // transposed scatter (inline W^T)
    Bs[wn4 + 1][wkrow] = f2bf(wv.y);
    Bs[wn4 + 2][wkrow] = f2bf(wv.z);
    Bs[wn4 + 3][wkrow] = f2bf(wv.w);
    __syncthreads();

    short8v af[2], bfr[2];
#pragma unroll
    for (int mi = 0; mi < 2; ++mi)
      af[mi] = *reinterpret_cast<const short8v*>(&As[wr * 32 + mi * 16 + r16][hi * 8]);
#pragma unroll
    for (int ni = 0; ni < 2; ++ni)
      bfr[ni] = *reinterpret_cast<const short8v*>(&Bs[wc * 32 + ni * 16 + r16][hi * 8]);
#pragma unroll
    for (int mi = 0; mi < 2; ++mi)
#pragma unroll
      for (int ni = 0; ni < 2; ++ni)
        acc[mi][ni] = __builtin_amdgcn_mfma_f32_16x16x32_bf16(
            af[mi], bfr[ni], acc[mi][ni], 0, 0, 0);
  }

#pragma unroll
  for (int mi = 0; mi < 2; ++mi)
#pragma unroll
    for (int ni = 0; ni < 2; ++ni)
#pragma unroll
      for (int r = 0; r < 4; ++r) {
        int gi = i0 + wr * 32 + mi * 16 + hi * 4 + r;   // C/D: col=lane&15, row=(lane>>4)*4+reg
        int gn = n0 + wc * 32 + ni * 16 + r16;
        m[(size_t)gi * NCOL + gn] = acc[mi][ni][r];
      }
}

// ---------------------------------------------------------------------------
// K2: pairwise L1 + exp, final output.  256 blocks x 512 thr.
// Block bi owns 4 i-rows.  Thread: k = t&31, jc = t>>5 (16 j-chunks of 64),
// keeps all 4 i-row fragments in registers (each m[j] load serves 4 exps).
// LDS-reduce the 16 jc partials, write out[i][2048+k] directly.
// m is 1 MB -> L1/L2-resident; VALU-bound.
// ---------------------------------------------------------------------------
__global__ __launch_bounds__(NTHR) void k2_pairwise(
    const float* __restrict__ m, float* __restrict__ out) {
  __shared__ float red[16][4][NK + 1];   // [jc][row][k]

  int bi = blockIdx.x;
  int t = threadIdx.x;
  int k  = t & 31;
  int jc = t >> 5;          // 0..15
  int i0 = bi * 4;
  int j0 = jc * 64;

  const float4* mv = reinterpret_cast<const float4*>(m);  // m[i][c]: idx = i*64 + c4
  float4 a0[4], a1[4];
#pragma unroll
  for (int r = 0; r < 4; ++r) {
    a0[r] = mv[(size_t)(i0 + r) * 64 + k * 2];
    a1[r] = mv[(size_t)(i0 + r) * 64 + k * 2 + 1];
  }

  float acc[4] = {0.f, 0.f, 0.f, 0.f};
#pragma unroll 2
  for (int jj = 0; jj < 64; ++jj) {
    int j = j0 + jj;
    float4 c0 = mv[(size_t)j * 64 + k * 2];
    float4 c1 = mv[(size_t)j * 64 + k * 2 + 1];
#pragma unroll
    for (int r = 0; r < 4; ++r) {
      float s = fabsf(a0[r].x - c0.x) + fabsf(a0[r].y - c0.y) +
                fabsf(a0[r].z - c0.z) + fabsf(a0[r].w - c0.w) +
                fabsf(a1[r].x - c1.x) + fabsf(a1[r].y - c1.y) +
                fabsf(a1[r].z - c1.z) + fabsf(a1[r].w - c1.w);
      acc[r] += __expf(-s);
    }
  }

#pragma unroll
  for (int r = 0; r < 4; ++r) red[jc][r][k] = acc[r];
  __syncthreads();

  if (t < 128) {
    int r = t >> 5, kk = t & 31;
    float s = 0.f;
#pragma unroll
    for (int c = 0; c < 16; ++c) s += red[c][r][kk];
    out[(size_t)(i0 + r) * OUTF + F_SZ + kk] = s;
  }
}

extern "C" void kernel_launch(void* const* d_in, const int* in_sizes, int n_in,
                              void* d_out, int out_size, void* d_ws, size_t ws_size,
                              hipStream_t stream) {
  const float* x = (const float*)d_in[0];
  const float* W = (const float*)d_in[1];
  float* out = (float*)d_out;
  float* m = (float*)d_ws;    // 1 MB

  k1_gemm_copy<<<dim3(256), NTHR, 0, stream>>>(x, W, m, out);
  k2_pairwise<<<dim3(256), NTHR, 0, stream>>>(m, out);
}

// Round 5
// 42.272 us; speedup vs baseline: 3.4122x; 1.9485x over previous
//
#include <hip/hip_runtime.h>
#include <hip/hip_bf16.h>

#define B_SZ 1024
#define F_SZ 2048
#define NK   32
#define NCOL 256            // NK*KD
#define OUTF 2080           // F + NK

typedef __attribute__((ext_vector_type(8))) short short8v;
typedef __attribute__((ext_vector_type(4))) float f32x4;

static __device__ __forceinline__ unsigned short f2bf(float v) {
  __hip_bfloat16 h = __float2bfloat16(v);   // RNE
  return reinterpret_cast<unsigned short&>(h);
}

// ---------------------------------------------------------------------------
// K1: barrier-free GEMM.  m[1024][256] = x[1024][2048] . W[2048][256], bf16 MFMA.
// 256 blocks x 512 thr.  Block = 32x32 output tile (mt=bid&31 -> x-slice stays
// on one XCD L2; W re-reads served by L2/L3).  8 waves split K: wave w owns
// k in [w*256, w*256+256), accumulates its own 2x2 16x16x32 frags from DIRECT
// global->reg loads (no LDS staging, no main-loop barriers).  One final
// __syncthreads for the 8-way LDS accumulator reduce.
// ---------------------------------------------------------------------------
__global__ __launch_bounds__(512) void k1_gemm(
    const float* __restrict__ x, const float* __restrict__ W,
    float* __restrict__ m) {
  __shared__ float red[8][16][64];   // [wave][reg][lane] = 32 KB

  int bid = blockIdx.x;
  int mt = bid & 31, nt = bid >> 5;
  int i0 = mt * 32, n0 = nt * 32;

  int t = threadIdx.x;
  int w = t >> 6, l = t & 63;
  int hi = l >> 4;          // 0..3 -> k-offset hi*8
  int r16 = l & 15;
  int hi8 = hi * 8;

  f32x4 acc[2][2];
#pragma unroll
  for (int mi = 0; mi < 2; ++mi)
#pragma unroll
    for (int ni = 0; ni < 2; ++ni) acc[mi][ni] = (f32x4)(0.f);

  // wave-private K-chunk: 8 steps of BK=32, no barriers
  for (int ks = 0; ks < 8; ++ks) {
    int kc = w * 256 + ks * 32;

    short8v af[2];
#pragma unroll
    for (int mi = 0; mi < 2; ++mi) {
      const float* ap = &x[(size_t)(i0 + mi * 16 + r16) * F_SZ + kc + hi8];
      float4 v0 = *reinterpret_cast<const float4*>(ap);
      float4 v1 = *reinterpret_cast<const float4*>(ap + 4);
      af[mi][0] = (short)f2bf(v0.x); af[mi][1] = (short)f2bf(v0.y);
      af[mi][2] = (short)f2bf(v0.z); af[mi][3] = (short)f2bf(v0.w);
      af[mi][4] = (short)f2bf(v1.x); af[mi][5] = (short)f2bf(v1.y);
      af[mi][6] = (short)f2bf(v1.z); af[mi][7] = (short)f2bf(v1.w);
    }

    short8v bfr[2];
#pragma unroll
    for (int ni = 0; ni < 2; ++ni) {
      int n = n0 + ni * 16 + r16;
      float wv[8];
#pragma unroll
      for (int u = 0; u < 8; ++u)      // 4 cache lines per instr (4 rows x 64B)
        wv[u] = W[(size_t)(kc + hi8 + u) * NCOL + n];
#pragma unroll
      for (int u = 0; u < 8; ++u) bfr[ni][u] = (short)f2bf(wv[u]);
    }

#pragma unroll
    for (int mi = 0; mi < 2; ++mi)
#pragma unroll
      for (int ni = 0; ni < 2; ++ni)
        acc[mi][ni] = __builtin_amdgcn_mfma_f32_16x16x32_bf16(
            af[mi], bfr[ni], acc[mi][ni], 0, 0, 0);
  }

  // 8-way wave reduce through LDS (one barrier total)
#pragma unroll
  for (int mi = 0; mi < 2; ++mi)
#pragma unroll
    for (int ni = 0; ni < 2; ++ni)
#pragma unroll
      for (int r = 0; r < 4; ++r)
        red[w][mi * 8 + ni * 4 + r][l] = acc[mi][ni][r];   // 64 lanes x 4B contig: conflict-free
  __syncthreads();

#pragma unroll
  for (int s = 0; s < 2; ++s) {
    int slot = t + s * 512;            // 1024 slots = 16 regs x 64 lanes
    int reg = slot >> 6, lane = slot & 63;
    float v = 0.f;
#pragma unroll
    for (int ww = 0; ww < 8; ++ww) v += red[ww][reg][lane];
    int mi = reg >> 3, ni = (reg >> 2) & 1, r = reg & 3;
    int row = i0 + mi * 16 + (lane >> 4) * 4 + r;   // C/D: col=lane&15, row=(lane>>4)*4+reg
    int col = n0 + ni * 16 + (lane & 15);
    m[(size_t)row * NCOL + col] = v;
  }
}

// ---------------------------------------------------------------------------
// K2: role-split 384 blocks x 1024 thr.
//   blocks 0..255   : pairwise L1+exp.  Block = 4 i-rows; thread (jc=t>>5 of 32
//                     chunks x 32 j, k=t&31); 4-row register frags so each 32B
//                     m[j] load serves 4 exps; LDS reduce; direct out write.
//                     16 waves/block = 4/SIMD for latency hiding.
//   blocks 256..383 : copy x rows into out[:, 0:2048] (memory-pipe work that
//                     overlaps pairwise's VALU on shared CUs).
// ---------------------------------------------------------------------------
__global__ __launch_bounds__(1024) void k2_pairwise_copy(
    const float* __restrict__ m, const float* __restrict__ x,
    float* __restrict__ out) {
  __shared__ float red[32][4][33];   // [jc][row][k] = 16.9 KB

  int bid = blockIdx.x;
  int t = threadIdx.x;

  if (bid >= 256) {
    // ------- copy role: 128 blocks x 1024 thr, 4 float4 each -------
    const float4* x4 = reinterpret_cast<const float4*>(x);
    int idx = (bid - 256) * 1024 + t;
#pragma unroll
    for (int it = 0; it < 4; ++it, idx += 128 * 1024) {
      int i  = idx >> 9;          // 512 float4 per x row
      int c4 = idx & 511;
      float4 v = x4[idx];
      *reinterpret_cast<float4*>(&out[(size_t)i * OUTF + c4 * 4]) = v;
    }
    return;
  }

  int k  = t & 31;
  int jc = t >> 5;          // 0..31
  int i0 = bid * 4;
  int j0 = jc * 32;

  const float4* mv = reinterpret_cast<const float4*>(m);  // m[i][c]: idx = i*64 + c4
  float4 a0[4], a1[4];
#pragma unroll
  for (int r = 0; r < 4; ++r) {
    a0[r] = mv[(size_t)(i0 + r) * 64 + k * 2];
    a1[r] = mv[(size_t)(i0 + r) * 64 + k * 2 + 1];
  }

  float acc[4] = {0.f, 0.f, 0.f, 0.f};
#pragma unroll 2
  for (int jj = 0; jj < 32; ++jj) {
    int j = j0 + jj;
    float4 c0 = mv[(size_t)j * 64 + k * 2];
    float4 c1 = mv[(size_t)j * 64 + k * 2 + 1];
#pragma unroll
    for (int r = 0; r < 4; ++r) {
      float s = fabsf(a0[r].x - c0.x) + fabsf(a0[r].y - c0.y) +
                fabsf(a0[r].z - c0.z) + fabsf(a0[r].w - c0.w) +
                fabsf(a1[r].x - c1.x) + fabsf(a1[r].y - c1.y) +
                fabsf(a1[r].z - c1.z) + fabsf(a1[r].w - c1.w);
      acc[r] += __expf(-s);
    }
  }

#pragma unroll
  for (int r = 0; r < 4; ++r) red[jc][r][k] = acc[r];
  __syncthreads();

  if (t < 128) {
    int r = t >> 5, kk = t & 31;
    float s = 0.f;
#pragma unroll
    for (int c = 0; c < 32; ++c) s += red[c][r][kk];
    out[(size_t)(i0 + r) * OUTF + F_SZ + kk] = s;
  }
}

extern "C" void kernel_launch(void* const* d_in, const int* in_sizes, int n_in,
                              void* d_out, int out_size, void* d_ws, size_t ws_size,
                              hipStream_t stream) {
  const float* x = (const float*)d_in[0];
  const float* W = (const float*)d_in[1];
  float* out = (float*)d_out;
  float* m = (float*)d_ws;    // 1 MB

  k1_gemm<<<dim3(256), 512, 0, stream>>>(x, W, m);
  k2_pairwise_copy<<<dim3(384), 1024, 0, stream>>>(m, x, out);
}